// Round 14
// baseline (641.853 us; speedup 1.0000x reference)
//
#include <hip/hip_runtime.h>
#include <math.h>

typedef __attribute__((ext_vector_type(8)))  short  short8;
typedef __attribute__((ext_vector_type(4)))  short  short4v;
typedef __attribute__((ext_vector_type(16))) float  f32x16;
typedef __attribute__((ext_vector_type(4)))  float  f32x4v;

#define DT_F    ((float)(1.0/96.0))
#define SQDT_F  (0.10206207261596575f)
#define DF_F    (0.99968754882437816f)
#define RFR_F   (0.03f)

// LDS byte layout: [bufL0 | bufH0 | bufL1 | bufH1 | sS[2][64] | sHc[64]]
#define LDS_L1  32768
#define LDS_H1  49152
#define LDS_SS  65536
#define LDS_HC  66048

static __device__ __forceinline__ short f2bf(float x) {
    return __builtin_bit_cast(short, (__bf16)x);
}
static __device__ __forceinline__ float bf2f(short h) {
    return (float)__builtin_bit_cast(__bf16, h);
}
static __device__ __forceinline__ short8 ldsr16(const char* p) {
    return *(const short8*)__builtin_assume_aligned(p, 16);
}
static __device__ __forceinline__ void ldsw8(char* p, short4v v) {
    *(short4v*)__builtin_assume_aligned(p, 8) = v;
}

// barrier with LDS-visibility only: does NOT drain vmcnt (prefetches stay in flight)
static __device__ __forceinline__ void soft_barrier() {
    asm volatile("" ::: "memory");
    asm volatile("s_waitcnt lgkmcnt(0)" ::: "memory");
    __builtin_amdgcn_s_barrier();
    asm volatile("" ::: "memory");
}

// issue A-frag loads for TWO row-blocks (a2, a2+1) of one hidden layer
static __device__ __forceinline__ void prefA2(const ushort* __restrict__ Wm,
        int a2, int l, short8 (&__restrict__ wf)[16])
{
    const short8* fb = (const short8*)(Wm + (a2 << 12));
#pragma unroll
    for (int kc = 0; kc < 8; ++kc) {
        wf[kc]     = fb[kc * 64 + l];         // row-block a2
        wf[8 + kc] = fb[512 + kc * 64 + l];   // row-block a2+1
    }
}

// layer 1: [t,S] -> 128 rows; wave wvm owns rows 32*wvm..+32 (one short8 per cc)
__device__ __forceinline__ void layer1(const float* __restrict__ Win, const float* __restrict__ bin_,
        float t, const float* __restrict__ sScur, char* __restrict__ lds, int wl1, int wvm, int l)
{
    const int g = l >> 4, c15 = l & 15;
    const int r0 = (wvm << 5) + (g << 3);
    float a8[8], w1[8];
#pragma unroll
    for (int jj = 0; jj < 8; ++jj) {
        const int r = r0 + jj;
        a8[jj] = fmaf(Win[2*r], t, bin_[r]);
        w1[jj] = Win[2*r + 1];
    }
#pragma unroll
    for (int cc = 0; cc < 4; ++cc) {
        const float S = sScur[c15 + (cc << 4)];
        short8 v;
#pragma unroll
        for (int jj = 0; jj < 8; ++jj) {
            float h = fmaf(w1[jj], S, a8[jj]);
            h = fmaxf(h, 0.01f * h);            // leaky relu
            v[jj] = f2bf(h);
        }
        *(short8*)__builtin_assume_aligned(lds + wl1 + (cc << 12), 16) = v;
    }
}

// hidden 128x128 layer, 2x2 wave grid: this wave computes rows 32*a2..+64, cols 32*b..+32.
// B-reads: 8 ds_read_b128 (shared by both row-blocks). Bias as C-init, e/o ILP split.
__device__ __forceinline__ void hidden32(char* __restrict__ lds,
        const int (&__restrict__ rdk)[8], const int (&__restrict__ wrq)[4],
        int rdImm, int wrImm,
        const short8 (&__restrict__ wf)[16], const float* __restrict__ bias,
        int a2, int l5)
{
    f32x16 e0, e1;
    f32x16 o0 = {0,0,0,0,0,0,0,0,0,0,0,0,0,0,0,0};
    f32x16 o1 = o0;
#pragma unroll
    for (int q = 0; q < 4; ++q) {
        const f32x4v b0 = *(const f32x4v*)&bias[(a2 << 5) + (q << 3) + (l5 << 2)];
        const f32x4v b1 = *(const f32x4v*)&bias[((a2 + 1) << 5) + (q << 3) + (l5 << 2)];
#pragma unroll
        for (int ii = 0; ii < 4; ++ii) {
            e0[(q << 2) + ii] = b0[ii];
            e1[(q << 2) + ii] = b1[ii];
        }
    }
#pragma unroll
    for (int kc = 0; kc < 8; kc += 2) {
        short8 be = ldsr16(lds + rdk[kc]     + rdImm);
        short8 bo = ldsr16(lds + rdk[kc + 1] + rdImm);
        e0 = __builtin_amdgcn_mfma_f32_32x32x16_bf16(wf[kc],         be, e0, 0, 0, 0);
        e1 = __builtin_amdgcn_mfma_f32_32x32x16_bf16(wf[8 + kc],     be, e1, 0, 0, 0);
        o0 = __builtin_amdgcn_mfma_f32_32x32x16_bf16(wf[kc + 1],     bo, o0, 0, 0, 0);
        o1 = __builtin_amdgcn_mfma_f32_32x32x16_bf16(wf[8 + kc + 1], bo, o1, 0, 0, 0);
    }
    const f32x16 acc0 = e0 + o0;
    const f32x16 acc1 = e1 + o1;
#pragma unroll
    for (int q = 0; q < 4; ++q) {
        short4v v0, v1;
#pragma unroll
        for (int ii = 0; ii < 4; ++ii) {
            float x0 = acc0[(q << 2) + ii]; v0[ii] = f2bf(fmaxf(x0, 0.01f * x0));
            float x1 = acc1[(q << 2) + ii]; v1[ii] = f2bf(fmaxf(x1, 0.01f * x1));
        }
        ldsw8(lds + wrq[q] + wrImm,        v0);          // row-block a2
        ldsw8(lds + (wrq[q] ^ 64) + wrImm, v1);          // row-block a2+1 (bit-6 field flip)
    }
}

__global__ __launch_bounds__(512, 2)
void sim_kernel(const float* __restrict__ normals, const float* __restrict__ strikes,
                const float* __restrict__ levWin, const float* __restrict__ levbin,
                const float* __restrict__ levbh,  const float* __restrict__ levWout,
                const float* __restrict__ levbout,
                const float* __restrict__ hedWin, const float* __restrict__ hedbin,
                const float* __restrict__ hedbh,  const float* __restrict__ hedbout,
                const ushort* __restrict__ WF, double* __restrict__ accD)
{
    __shared__ char lds[66560];
    float* sSb = (float*)(lds + LDS_SS);   // [2][64]
    float* sHc = (float*)(lds + LDS_HC);   // [64]

    const int tid  = threadIdx.x;
    const int wv   = tid >> 6;
    const int half = wv >> 2;      // 0 = lev chain, 1 = hed chain
    const int wvm  = wv & 3;
    const int a2   = wvm & 2;      // row-half base block (rows 32*a2..+64)
    const int bcol = wvm & 1;      // col-tile (cols 32*bcol..+32)
    const int l    = tid & 63;
    const int g    = l >> 4;
    const int c15  = l & 15;
    const int c0   = l & 31;
    const int l5   = l >> 5;
    const int bp0  = blockIdx.x * 64;

    // ---- loop-invariant swizzled LDS addresses (bytes) ----
    const int chainoff = half << 14;
    const int tileoff  = chainoff + (bcol << 13);
    const int rbase = tileoff + (c0 << 8) + ((l5 ^ (c0 & 1)) << 4);
    const int pxor  = ((c0 >> 1) & 7) << 5;
    int rdk[8];
#pragma unroll
    for (int kc = 0; kc < 8; ++kc) rdk[kc] = rbase + ((kc << 5) ^ pxor);
    int wrq[4];
#pragma unroll
    for (int q = 0; q < 4; ++q)
        wrq[q] = tileoff + (c0 << 8) + (l5 << 3)
               + ((q ^ (c0 & 3)) << 4) + ((a2 ^ ((c0 >> 2) & 3)) << 6);
    const int wl1 = chainoff + (c15 << 8) + ((g ^ (c15 & 3)) << 4)
                  + ((wvm ^ ((c15 >> 2) & 3)) << 6);
    int rout[4];
    if (half == 0) {
        const int cl = c15 + (wvm << 4);
        const int ob = LDS_L1 + (cl << 8) + ((g ^ ((cl >> 2) & 3)) << 6);
#pragma unroll
        for (int kb = 0; kb < 4; ++kb) rout[kb] = ob + ((kb ^ (cl & 3)) << 4);
    } else {
        const int ob = LDS_H1 + (c15 << 8) + (((l >> 4) ^ (c15 & 3)) << 4);
        const int px2 = ((c15 >> 2) & 3) << 6;
#pragma unroll
        for (int kcq = 0; kcq < 4; ++kcq) rout[kcq] = ob + ((kcq << 6) ^ px2);
    }

    if (tid < 64) sSb[tid] = 1.0f;   // sS[0]
    float hedg[4][4];
#pragma unroll
    for (int a = 0; a < 4; ++a)
#pragma unroll
        for (int b = 0; b < 4; ++b) hedg[a][b] = 0.f;
    float dfim1 = 1.0f;

    short8 wfA[16], wfB[16];   // phase-ahead A-frag pipeline (2 row-blocks each)
    __syncthreads();

    for (int i = 1; i <= 96; ++i) {
        const int idx = (i - 1) / 12;
        const float t = (float)(i - 1) * DT_F;
        const float* sScur = sSb + (((i - 1) & 1) << 6);
        float* sSnxt = sSb + ((i & 1) << 6);
        const ushort* WFi = WF + (size_t)idx * 106496;

        const float* Win  = (half ? hedWin : levWin) + idx * 256;
        const float* binp = (half ? hedbin : levbin) + (idx << 7);
        const float* bh   = (half ? hedbh  : levbh)  + idx * 384;
        const ushort* Wm  = WFi + ((half * 3) << 14);

        // W1: issue h1 frag loads; layer1 VALU hides them; normals prefetch (lev)
        prefA2(Wm, a2, l, wfA);
        layer1(Win, binp, t, sScur, lds, wl1, wvm, l);
        float nrm = 0.f;
        if (half == 0) nrm = normals[(size_t)(i - 1) * 16384 + bp0 + c15 + (wvm << 4)];
        soft_barrier();                                     // b1

        // W2: issue h2 loads; compute h1
        prefA2(Wm + 16384, a2, l, wfB);
        hidden32(lds, rdk, wrq, 0,     32768, wfA, bh,       a2, l5);
        soft_barrier();                                     // b2

        // W3: issue h3 loads; compute h2
        prefA2(Wm + 32768, a2, l, wfA);
        hidden32(lds, rdk, wrq, 32768, 0,     wfB, bh + 128, a2, l5);
        soft_barrier();                                     // b3

        // W4: issue hed-out operand loads; compute h3
        short8 wOut[4];
        f32x4v bo4;
        if (half == 1) {
            const short8* fo = (const short8*)(WFi + 98304 + (wvm << 11));
#pragma unroll
            for (int kcq = 0; kcq < 4; ++kcq) wOut[kcq] = fo[kcq * 64 + l];
            bo4 = *(const f32x4v*)&hedbout[(idx << 6) + (wvm << 4) + (g << 2)];
        }
        hidden32(lds, rdk, wrq, 0,     32768, wfA, bh + 256, a2, l5);
        soft_barrier();                                     // b4

        const float dfi = dfim1 * DF_F;
        f32x4v acc0, acc1, acc2, acc3;
        if (half == 0) {
            // lev-out (1x128 dot) + SDE; wave wvm owns cols 16*wvm..+16
            const float* Wo = levWout + (idx << 7);
            float wk[32];
#pragma unroll
            for (int kb = 0; kb < 8; ++kb)
                *(f32x4v*)&wk[4 * kb] = *(const f32x4v*)&Wo[(g << 5) + (kb << 2)];
            const int c = c15 + (wvm << 4);
            float p = 0.f;
#pragma unroll
            for (int kb = 0; kb < 4; ++kb) {
                short8 hv = ldsr16(lds + rout[kb]);   // logical kb (addr pre-XORed)
#pragma unroll
                for (int j = 0; j < 8; ++j) p = fmaf(bf2f(hv[j]), wk[(kb << 3) + j], p);
            }
            p += __shfl_xor(p, 16);
            p += __shfl_xor(p, 32);
            p += levbout[idx];
            const float lv = (p > 20.f) ? p : __logf(1.f + __expf(p));   // softplus
            const float S = sScur[c];
            const float drift = S * RFR_F / (1.f + fabsf(S * RFR_F) * SQDT_F);
            const float dif   = S * lv    / (1.f + fabsf(S * lv)   * SQDT_F);
            const float dW = SQDT_F * nrm;
            const float Sn = S + drift * DT_F + dif * dW;
            if (g == 0) { sSnxt[c] = Sn; sHc[c] = dfim1 * (S * dif) * dW; }
        } else {
            // hed-out 64x128 via 16x16x32 MFMA; prefetched wOut, bias as C-init
            acc0 = bo4; acc1 = bo4; acc2 = bo4; acc3 = bo4;
            __builtin_amdgcn_s_setprio(1);
#pragma unroll
            for (int kcq = 0; kcq < 4; ++kcq) {
                short8 b0 = ldsr16(lds + rout[kcq]);
                short8 b1 = ldsr16(lds + rout[kcq] + 4096);
                short8 b2 = ldsr16(lds + rout[kcq] + 8192);
                short8 b3 = ldsr16(lds + rout[kcq] + 12288);
                acc0 = __builtin_amdgcn_mfma_f32_16x16x32_bf16(wOut[kcq], b0, acc0, 0, 0, 0);
                acc1 = __builtin_amdgcn_mfma_f32_16x16x32_bf16(wOut[kcq], b1, acc1, 0, 0, 0);
                acc2 = __builtin_amdgcn_mfma_f32_16x16x32_bf16(wOut[kcq], b2, acc2, 0, 0, 0);
                acc3 = __builtin_amdgcn_mfma_f32_16x16x32_bf16(wOut[kcq], b3, acc3, 0, 0, 0);
            }
            __builtin_amdgcn_s_setprio(0);
        }
        soft_barrier();                                     // b5

        if (half == 1) {
            const float hc0 = sHc[c15], hc1 = sHc[16 + c15], hc2 = sHc[32 + c15], hc3 = sHc[48 + c15];
#pragma unroll
            for (int ii = 0; ii < 4; ++ii) {
                hedg[0][ii] = fmaf(hc0, acc0[ii], hedg[0][ii]);
                hedg[1][ii] = fmaf(hc1, acc1[ii], hedg[1][ii]);
                hedg[2][ii] = fmaf(hc2, acc2[ii], hedg[2][ii]);
                hedg[3][ii] = fmaf(hc3, acc3[ii], hedg[3][ii]);
            }
            if ((i % 12) == 0) {
                const int m = i / 12 - 1;
                const int isel = m & 3;
                const bool active = ((m >> 2) == (g & 1));
                const int ks = (wvm << 1) + (g >> 1);
                float s_ = 0.f, q_ = 0.f;
                if (active) {
                    const float K = strikes[ks];
#pragma unroll
                    for (int ct = 0; ct < 4; ++ct) {
                        const float* hrow = hedg[ct];
                        const float hv = (isel == 0) ? hrow[0] : (isel == 1) ? hrow[1]
                                        : (isel == 2) ? hrow[2] : hrow[3];
                        const float Sn = sSnxt[(ct << 4) + c15];
                        const float sim = dfi * fmaxf(Sn - K, 0.f) - hv;
                        s_ += sim; q_ += sim * sim;
                    }
                }
#pragma unroll
                for (int off = 1; off < 16; off <<= 1) {
                    s_ += __shfl_xor(s_, off);
                    q_ += __shfl_xor(q_, off);
                }
                if (active && c15 == 0) {
                    const int rep = blockIdx.x & 31;
                    atomicAdd(&accD[rep * 128 + ks * 8 + m], (double)s_);
                    atomicAdd(&accD[rep * 128 + 64 + ks * 8 + m], (double)q_);
                }
            }
        }
        dfim1 = dfi;
    }
}

// prep: pack bf16 weights into MFMA fragment order + zero accumulators (unchanged layout)
__global__ void prep_kernel(const float* __restrict__ levWh, const float* __restrict__ hedWh,
                            const float* __restrict__ hedWout,
                            ushort* __restrict__ WF, double* __restrict__ accD)
{
    const long long stride = (long long)gridDim.x * blockDim.x;
    const long long t0 = (long long)blockIdx.x * blockDim.x + threadIdx.x;
    for (long long e = t0; e < 851968LL; e += stride) {
        const int idx = (int)(e / 106496);
        const int rem = (int)(e % 106496);
        float val;
        if (rem < 98304) {                        // 6 hidden matrices
            const int m    = rem >> 14;
            const int r2   = rem & 16383;
            const int slot = r2 >> 9;             // rb*8 + kc
            const int rb   = slot >> 3;
            const int kc   = slot & 7;
            const int lane = (r2 >> 3) & 63;
            const int j    = r2 & 7;
            const int r = (rb << 5) + (lane & 31);
            const int k = (kc << 4) + ((lane >> 5) << 3) + j;
            const float* src = (m < 3) ? levWh : hedWh;
            const int mm = (m < 3) ? m : m - 3;
            val = src[(((idx * 3 + mm) << 7) + r) * 128 + k];
        } else {                                  // hed-out 64x128
            const int r3   = rem - 98304;
            const int slot = r3 >> 9;             // rb*4 + kcq
            const int rb   = slot >> 2;
            const int kcq  = slot & 3;
            const int lane = (r3 >> 3) & 63;
            const int j    = r3 & 7;
            const int r = (rb << 4) + (lane & 15);
            const int k = (kcq << 5) + ((lane >> 4) << 3) + j;
            val = hedWout[(idx << 13) + (r << 7) + k];
        }
        WF[e] = (ushort)f2bf(val);
    }
    for (long long e = t0; e < 4096; e += stride) accD[e] = 0.0;
}

__global__ void finalize_kernel(const double* __restrict__ accD, float* __restrict__ out)
{
    const int t = threadIdx.x;
    if (t < 64) {
        double s = 0.0, q = 0.0;
        for (int rep = 0; rep < 32; ++rep) {
            s += accD[rep * 128 + t];
            q += accD[rep * 128 + 64 + t];
        }
        out[t]      = (float)(s / 16384.0);
        out[64 + t] = (float)((q - s * s / 16384.0) / 16383.0);
    }
}

extern "C" void kernel_launch(void* const* d_in, const int* in_sizes, int n_in,
                              void* d_out, int out_size, void* d_ws, size_t ws_size,
                              hipStream_t stream)
{
    const float* normals = (const float*)d_in[0];
    const float* strikes = (const float*)d_in[1];
    const float* levWin  = (const float*)d_in[2];
    const float* levbin  = (const float*)d_in[3];
    const float* levWh   = (const float*)d_in[4];
    const float* levbh   = (const float*)d_in[5];
    const float* levWout = (const float*)d_in[6];
    const float* levbout = (const float*)d_in[7];
    const float* hedWin  = (const float*)d_in[8];
    const float* hedbin  = (const float*)d_in[9];
    const float* hedWh   = (const float*)d_in[10];
    const float* hedbh   = (const float*)d_in[11];
    const float* hedWout = (const float*)d_in[12];
    const float* hedbout = (const float*)d_in[13];

    ushort* WF   = (ushort*)d_ws;                      // 851,968 ushorts = 1,703,936 B
    double* accD = (double*)((char*)d_ws + 1703936);   // 4096 doubles

    prep_kernel<<<1024, 256, 0, stream>>>(levWh, hedWh, hedWout, WF, accD);
    sim_kernel<<<256, 512, 0, stream>>>(normals, strikes,
                                        levWin, levbin, levbh, levWout, levbout,
                                        hedWin, hedbin, hedbh, hedbout,
                                        WF, accD);
    finalize_kernel<<<1, 64, 0, stream>>>(accD, (float*)d_out);
}

// Round 15
// 542.513 us; speedup vs baseline: 1.1831x; 1.1831x over previous
//
#include <hip/hip_runtime.h>
#include <math.h>

typedef __attribute__((ext_vector_type(8)))  short  short8;
typedef __attribute__((ext_vector_type(4)))  short  short4v;
typedef __attribute__((ext_vector_type(16))) float  f32x16;
typedef __attribute__((ext_vector_type(4)))  float  f32x4v;

#define DT_F    ((float)(1.0/96.0))
#define SQDT_F  (0.10206207261596575f)
#define DF_F    (0.99968754882437816f)
#define RFR_F   (0.03f)

// LDS byte layout: [bufL0 | bufH0 | bufL1 | bufH1 | sS[2][64] | sHc[64]]
#define LDS_L1  32768
#define LDS_SS  65536
#define LDS_HC  66048

static __device__ __forceinline__ short f2bf(float x) {
    return __builtin_bit_cast(short, (__bf16)x);
}
static __device__ __forceinline__ float bf2f(short h) {
    return (float)__builtin_bit_cast(__bf16, h);
}
static __device__ __forceinline__ short8 ldsr16(const char* p) {
    return *(const short8*)__builtin_assume_aligned(p, 16);
}
static __device__ __forceinline__ void ldsw8(char* p, short4v v) {
    *(short4v*)__builtin_assume_aligned(p, 8) = v;
}

// barrier with LDS-visibility only: does NOT drain vmcnt (prefetches stay in flight)
static __device__ __forceinline__ void soft_barrier() {
    asm volatile("" ::: "memory");
    asm volatile("s_waitcnt lgkmcnt(0)" ::: "memory");
    __builtin_amdgcn_s_barrier();
    asm volatile("" ::: "memory");
}

// issue one hidden layer's A-frag loads (consumed one phase later)
static __device__ __forceinline__ void prefA(const ushort* __restrict__ Wm,
        int wvm, int l, short8 (&__restrict__ wf)[8])
{
    const short8* fb = (const short8*)(Wm + (wvm << 12));   // rb = wvm
#pragma unroll
    for (int kc = 0; kc < 8; ++kc) wf[kc] = fb[kc * 64 + l];
}

// layer 1: [t,S] -> 128 rows; wave wvm owns rows 32*wvm..+32 (one short8 per cc)
__device__ __forceinline__ void layer1(const float* __restrict__ Win, const float* __restrict__ bin_,
        float t, const float* __restrict__ sScur, char* __restrict__ lds, int wl1, int wvm, int l)
{
    const int g = l >> 4, c15 = l & 15;
    const int r0 = (wvm << 5) + (g << 3);
    float a8[8], w1[8];
#pragma unroll
    for (int jj = 0; jj < 8; ++jj) {
        const int r = r0 + jj;
        a8[jj] = fmaf(Win[2*r], t, bin_[r]);
        w1[jj] = Win[2*r + 1];
    }
#pragma unroll
    for (int cc = 0; cc < 4; ++cc) {
        const float S = sScur[c15 + (cc << 4)];
        short8 v;
#pragma unroll
        for (int jj = 0; jj < 8; ++jj) {
            float h = fmaf(w1[jj], S, a8[jj]);
            h = fmaxf(h, 0.01f * h);            // leaky relu
            v[jj] = f2bf(h);
        }
        *(short8*)__builtin_assume_aligned(lds + wl1 + (cc << 12), 16) = v;
    }
}

// hidden 128x128 layer: prefetched A-frags, precomputed LDS addrs, bias as C-init, 4 acc chains
__device__ __forceinline__ void hidden32(char* __restrict__ lds,
        const int (&__restrict__ rdk)[8], const int (&__restrict__ wrq)[4],
        int rdImm, int wrImm,
        const short8 (&__restrict__ wf)[8], const float* __restrict__ bias,
        int wvm, int l, int l5)
{
    f32x16 a0e, a1e;
    f32x16 a0o = {0,0,0,0,0,0,0,0,0,0,0,0,0,0,0,0};
    f32x16 a1o = a0o;
#pragma unroll
    for (int q = 0; q < 4; ++q) {
        const f32x4v bq = *(const f32x4v*)&bias[(wvm << 5) + (q << 3) + (l5 << 2)];
#pragma unroll
        for (int ii = 0; ii < 4; ++ii) {
            a0e[(q << 2) + ii] = bq[ii];
            a1e[(q << 2) + ii] = bq[ii];
        }
    }
#pragma unroll
    for (int kc = 0; kc < 8; kc += 2) {
        short8 b0e = ldsr16(lds + rdk[kc]     + rdImm);
        short8 b1e = ldsr16(lds + rdk[kc]     + rdImm + 8192);
        short8 b0o = ldsr16(lds + rdk[kc + 1] + rdImm);
        short8 b1o = ldsr16(lds + rdk[kc + 1] + rdImm + 8192);
        a0e = __builtin_amdgcn_mfma_f32_32x32x16_bf16(wf[kc],     b0e, a0e, 0, 0, 0);
        a1e = __builtin_amdgcn_mfma_f32_32x32x16_bf16(wf[kc],     b1e, a1e, 0, 0, 0);
        a0o = __builtin_amdgcn_mfma_f32_32x32x16_bf16(wf[kc + 1], b0o, a0o, 0, 0, 0);
        a1o = __builtin_amdgcn_mfma_f32_32x32x16_bf16(wf[kc + 1], b1o, a1o, 0, 0, 0);
    }
    const f32x16 acc0 = a0e + a0o;
    const f32x16 acc1 = a1e + a1o;
#pragma unroll
    for (int q = 0; q < 4; ++q) {
        short4v o0, o1;
#pragma unroll
        for (int ii = 0; ii < 4; ++ii) {
            float x0 = acc0[(q << 2) + ii]; o0[ii] = f2bf(fmaxf(x0, 0.01f * x0));
            float x1 = acc1[(q << 2) + ii]; o1[ii] = f2bf(fmaxf(x1, 0.01f * x1));
        }
        ldsw8(lds + wrq[q] + wrImm,        o0);
        ldsw8(lds + wrq[q] + wrImm + 8192, o1);
    }
}

__global__ __launch_bounds__(512, 2)
void sim_kernel(const float* __restrict__ normals, const float* __restrict__ strikes,
                const float* __restrict__ levWin, const float* __restrict__ levbin,
                const float* __restrict__ levbh,  const float* __restrict__ levWout,
                const float* __restrict__ levbout,
                const float* __restrict__ hedWin, const float* __restrict__ hedbin,
                const float* __restrict__ hedbh,  const float* __restrict__ hedbout,
                const ushort* __restrict__ WF, double* __restrict__ accD)
{
    __shared__ char lds[66560];
    float* sSb = (float*)(lds + LDS_SS);   // [2][64]
    float* sHc = (float*)(lds + LDS_HC);   // [64]

    const int tid  = threadIdx.x;
    const int wv   = tid >> 6;
    const int half = wv >> 2;      // 0 = lev chain, 1 = hed chain
    const int wvm  = wv & 3;
    const int rb   = wvm >> 1;     // hed-out row-tile (strike-mat rows 32*rb..+32)
    const int cb   = wvm & 1;      // hed-out batch-col tile (cols 32*cb..+32)
    const int l    = tid & 63;
    const int g    = l >> 4;
    const int c15  = l & 15;
    const int c0   = l & 31;
    const int l5   = l >> 5;
    const int bp0  = blockIdx.x * 64;

    // ---- loop-invariant swizzled LDS addresses (bytes) ----
    const int chainoff = half << 14;
    const int rbase = chainoff + (c0 << 8) + ((l5 ^ (c0 & 1)) << 4);
    const int pxor  = ((c0 >> 1) & 7) << 5;
    int rdk[8];
#pragma unroll
    for (int kc = 0; kc < 8; ++kc) rdk[kc] = rbase + ((kc << 5) ^ pxor);
    int wrq[4];
#pragma unroll
    for (int q = 0; q < 4; ++q)
        wrq[q] = chainoff + (c0 << 8) + (l5 << 3)
               + ((q ^ (c0 & 3)) << 4) + ((wvm ^ ((c0 >> 2) & 3)) << 6);
    const int wl1 = chainoff + (c15 << 8) + ((g ^ (c15 & 3)) << 4)
                  + ((wvm ^ ((c15 >> 2) & 3)) << 6);
    int rout[4];
    if (half == 0) {
        const int cl = c15 + (wvm << 4);
        const int ob = LDS_L1 + (cl << 8) + ((g ^ ((cl >> 2) & 3)) << 6);
#pragma unroll
        for (int kb = 0; kb < 4; ++kb) rout[kb] = ob + ((kb ^ (cl & 3)) << 4);
    }
    // hed-out B reads: bufH[1] = chain base + 32768; +8192 for col-tile cb
    const int houtImm = 32768 + (cb << 13);

    if (tid < 64) sSb[tid] = 1.0f;   // sS[0]
    f32x16 hedg = {0,0,0,0,0,0,0,0,0,0,0,0,0,0,0,0};
    float dfim1 = 1.0f;

    short8 wfA[8], wfB[8];   // phase-ahead A-frag pipeline
    __syncthreads();

    for (int i = 1; i <= 96; ++i) {
        const int idx = (i - 1) / 12;
        const float t = (float)(i - 1) * DT_F;
        const float* sScur = sSb + (((i - 1) & 1) << 6);
        float* sSnxt = sSb + ((i & 1) << 6);
        const ushort* WFi = WF + (size_t)idx * 106496;

        const float* Win  = (half ? hedWin : levWin) + idx * 256;
        const float* binp = (half ? hedbin : levbin) + (idx << 7);
        const float* bh   = (half ? hedbh  : levbh)  + idx * 384;
        const ushort* Wm  = WFi + ((half * 3) << 14);

        // W1: issue h1 frag loads; layer1 VALU hides them; normals prefetch (lev)
        prefA(Wm, wvm, l, wfA);
        layer1(Win, binp, t, sScur, lds, wl1, wvm, l);
        float nrm = 0.f;
        if (half == 0) nrm = normals[(size_t)(i - 1) * 16384 + bp0 + c15 + (wvm << 4)];
        soft_barrier();                                     // b1

        // W2: issue h2 loads; compute h1
        prefA(Wm + 16384, wvm, l, wfB);
        hidden32(lds, rdk, wrq, 0,     32768, wfA, bh,       wvm, l, l5);
        soft_barrier();                                     // b2

        // W3: issue h3 loads; compute h2
        prefA(Wm + 32768, wvm, l, wfA);
        hidden32(lds, rdk, wrq, 32768, 0,     wfB, bh + 128, wvm, l, l5);
        soft_barrier();                                     // b3

        // W4: issue hed-out operand loads (32x32 frags + bias rows); compute h3
        short8 wOut[8];
        f32x4v boq[4];
        if (half == 1) {
            const short8* fo = (const short8*)(WFi + 98304 + (rb << 12));
#pragma unroll
            for (int kc = 0; kc < 8; ++kc) wOut[kc] = fo[kc * 64 + l];
#pragma unroll
            for (int qq = 0; qq < 4; ++qq)
                boq[qq] = *(const f32x4v*)&hedbout[(idx << 6) + (rb << 5) + (qq << 3) + (l5 << 2)];
        }
        hidden32(lds, rdk, wrq, 0,     32768, wfA, bh + 256, wvm, l, l5);
        soft_barrier();                                     // b4

        const float dfi = dfim1 * DF_F;
        f32x16 hacc;
        if (half == 0) {
            // lev-out (1x128 dot) + SDE; wave wvm owns cols 16*wvm..+16
            const float* Wo = levWout + (idx << 7);
            float wk[32];
#pragma unroll
            for (int kb = 0; kb < 8; ++kb)
                *(f32x4v*)&wk[4 * kb] = *(const f32x4v*)&Wo[(g << 5) + (kb << 2)];
            const int c = c15 + (wvm << 4);
            float p = 0.f;
#pragma unroll
            for (int kb = 0; kb < 4; ++kb) {
                short8 hv = ldsr16(lds + rout[kb]);   // logical kb (addr pre-XORed)
#pragma unroll
                for (int j = 0; j < 8; ++j) p = fmaf(bf2f(hv[j]), wk[(kb << 3) + j], p);
            }
            p += __shfl_xor(p, 16);
            p += __shfl_xor(p, 32);
            p += levbout[idx];
            const float lv = (p > 20.f) ? p : __logf(1.f + __expf(p));   // softplus
            const float S = sScur[c];
            const float drift = S * RFR_F / (1.f + fabsf(S * RFR_F) * SQDT_F);
            const float dif   = S * lv    / (1.f + fabsf(S * lv)   * SQDT_F);
            const float dW = SQDT_F * nrm;
            const float Sn = S + drift * DT_F + dif * dW;
            if (g == 0) { sSnxt[c] = Sn; sHc[c] = dfim1 * (S * dif) * dW; }
        } else {
            // hed-out 64x128 via 32x32x16 MFMA: wave (rb,cb) computes rows 32rb..+32, cols 32cb..+32
            // C-init = bias rows (q&3)+8(q>>2)+4*l5+32rb ; e/o ILP split
            f32x16 he, ho = {0,0,0,0,0,0,0,0,0,0,0,0,0,0,0,0};
#pragma unroll
            for (int qq = 0; qq < 4; ++qq)
#pragma unroll
                for (int ii = 0; ii < 4; ++ii) he[(qq << 2) + ii] = boq[qq][ii];
            __builtin_amdgcn_s_setprio(1);
#pragma unroll
            for (int kc = 0; kc < 8; kc += 2) {
                short8 be = ldsr16(lds + rdk[kc]     + houtImm);
                short8 bo = ldsr16(lds + rdk[kc + 1] + houtImm);
                he = __builtin_amdgcn_mfma_f32_32x32x16_bf16(wOut[kc],     be, he, 0, 0, 0);
                ho = __builtin_amdgcn_mfma_f32_32x32x16_bf16(wOut[kc + 1], bo, ho, 0, 0, 0);
            }
            __builtin_amdgcn_s_setprio(0);
            hacc = he + ho;
        }
        soft_barrier();                                     // b5

        if (half == 1) {
            // hedging: one batch-col per lane; row = (q&3)+8(q>>2)+4*l5+32rb
            const float hc = sHc[c0 + (cb << 5)];
#pragma unroll
            for (int q = 0; q < 16; ++q) hedg[q] = fmaf(hc, hacc[q], hedg[q]);
            if ((i % 12) == 0) {
                const int m = i / 12 - 1;
                const bool active = (l5 == (m >> 2));
                const float Sn = sSnxt[c0 + (cb << 5)];
#pragma unroll
                for (int sl = 0; sl < 4; ++sl) {           // strikes 4*rb + sl
                    float sv = 0.f;
                    if (active) {
                        const float K = strikes[(rb << 2) + sl];
                        sv = dfi * fmaxf(Sn - K, 0.f) - hedg[(sl << 2) + (m & 3)];
                    }
                    float qv = sv * sv;
#pragma unroll
                    for (int off = 1; off < 32; off <<= 1) {
                        sv += __shfl_xor(sv, off);
                        qv += __shfl_xor(qv, off);
                    }
                    if (active && c0 == 0) {
                        const int rep = blockIdx.x & 31;
                        const int ks = (rb << 2) + sl;
                        atomicAdd(&accD[rep * 128 + ks * 8 + m], (double)sv);
                        atomicAdd(&accD[rep * 128 + 64 + ks * 8 + m], (double)qv);
                    }
                }
            }
        }
        dfim1 = dfi;
    }
}

// prep: pack bf16 weights into MFMA fragment order + zero accumulators
// per idx (106496 ushorts): 6x [128x128] hidden (16384 each, 32x32x16 frags)
// then [64x128] hed-out as 32x32x16 frags: [rb(2)][kc(8)][lane(64)][j(8)]
__global__ void prep_kernel(const float* __restrict__ levWh, const float* __restrict__ hedWh,
                            const float* __restrict__ hedWout,
                            ushort* __restrict__ WF, double* __restrict__ accD)
{
    const long long stride = (long long)gridDim.x * blockDim.x;
    const long long t0 = (long long)blockIdx.x * blockDim.x + threadIdx.x;
    for (long long e = t0; e < 851968LL; e += stride) {
        const int idx = (int)(e / 106496);
        const int rem = (int)(e % 106496);
        float val;
        if (rem < 98304) {                        // 6 hidden matrices
            const int m    = rem >> 14;
            const int r2   = rem & 16383;
            const int slot = r2 >> 9;             // rb*8 + kc
            const int rbp  = slot >> 3;
            const int kc   = slot & 7;
            const int lane = (r2 >> 3) & 63;
            const int j    = r2 & 7;
            const int r = (rbp << 5) + (lane & 31);
            const int k = (kc << 4) + ((lane >> 5) << 3) + j;
            const float* src = (m < 3) ? levWh : hedWh;
            const int mm = (m < 3) ? m : m - 3;
            val = src[(((idx * 3 + mm) << 7) + r) * 128 + k];
        } else {                                  // hed-out 64x128, 32x32x16 frags
            const int r3   = rem - 98304;
            const int slot = r3 >> 9;             // rb*8 + kc
            const int rbp  = slot >> 3;
            const int kc   = slot & 7;
            const int lane = (r3 >> 3) & 63;
            const int j    = r3 & 7;
            const int r = (rbp << 5) + (lane & 31);
            const int k = (kc << 4) + ((lane >> 5) << 3) + j;
            val = hedWout[(idx << 13) + (r << 7) + k];
        }
        WF[e] = (ushort)f2bf(val);
    }
    for (long long e = t0; e < 4096; e += stride) accD[e] = 0.0;
}

__global__ void finalize_kernel(const double* __restrict__ accD, float* __restrict__ out)
{
    const int t = threadIdx.x;
    if (t < 64) {
        double s = 0.0, q = 0.0;
        for (int rep = 0; rep < 32; ++rep) {
            s += accD[rep * 128 + t];
            q += accD[rep * 128 + 64 + t];
        }
        out[t]      = (float)(s / 16384.0);
        out[64 + t] = (float)((q - s * s / 16384.0) / 16383.0);
    }
}

extern "C" void kernel_launch(void* const* d_in, const int* in_sizes, int n_in,
                              void* d_out, int out_size, void* d_ws, size_t ws_size,
                              hipStream_t stream)
{
    const float* normals = (const float*)d_in[0];
    const float* strikes = (const float*)d_in[1];
    const float* levWin  = (const float*)d_in[2];
    const float* levbin  = (const float*)d_in[3];
    const float* levWh   = (const float*)d_in[4];
    const float* levbh   = (const float*)d_in[5];
    const float* levWout = (const float*)d_in[6];
    const float* levbout = (const float*)d_in[7];
    const float* hedWin  = (const float*)d_in[8];
    const float* hedbin  = (const float*)d_in[9];
    const float* hedWh   = (const float*)d_in[10];
    const float* hedbh   = (const float*)d_in[11];
    const float* hedWout = (const float*)d_in[12];
    const float* hedbout = (const float*)d_in[13];

    ushort* WF   = (ushort*)d_ws;                      // 851,968 ushorts = 1,703,936 B
    double* accD = (double*)((char*)d_ws + 1703936);   // 4096 doubles

    prep_kernel<<<1024, 256, 0, stream>>>(levWh, hedWh, hedWout, WF, accD);
    sim_kernel<<<256, 512, 0, stream>>>(normals, strikes,
                                        levWin, levbin, levbh, levWout, levbout,
                                        hedWin, hedbin, hedbh, hedbout,
                                        WF, accD);
    finalize_kernel<<<1, 64, 0, stream>>>(accD, (float*)d_out);
}

// Round 16
// 535.883 us; speedup vs baseline: 1.1977x; 1.0124x over previous
//
#include <hip/hip_runtime.h>
#include <math.h>

typedef __attribute__((ext_vector_type(8)))  short  short8;
typedef __attribute__((ext_vector_type(4)))  short  short4v;
typedef __attribute__((ext_vector_type(16))) float  f32x16;
typedef __attribute__((ext_vector_type(4)))  float  f32x4v;

#define DT_F    ((float)(1.0/96.0))
#define SQDT_F  (0.10206207261596575f)
#define DF_F    (0.99968754882437816f)
#define RFR_F   (0.03f)

// LDS byte layout: [bufL0 | bufH0 | bufL1 | bufH1 | sS[2][64] | sHc[64]]
#define LDS_L1  32768
#define LDS_H1  49152
#define LDS_SS  65536
#define LDS_HC  66048

static __device__ __forceinline__ short f2bf(float x) {
    return __builtin_bit_cast(short, (__bf16)x);
}
static __device__ __forceinline__ float bf2f(short h) {
    return (float)__builtin_bit_cast(__bf16, h);
}
static __device__ __forceinline__ short8 ldsr16(const char* p) {
    return *(const short8*)__builtin_assume_aligned(p, 16);
}
static __device__ __forceinline__ void ldsw8(char* p, short4v v) {
    *(short4v*)__builtin_assume_aligned(p, 8) = v;
}

// barrier with LDS-visibility only: does NOT drain vmcnt, so prefetched
// global loads stay in flight across phases (T3/T4; validated correct in R8).
static __device__ __forceinline__ void soft_barrier() {
    asm volatile("" ::: "memory");
    asm volatile("s_waitcnt lgkmcnt(0)" ::: "memory");
    __builtin_amdgcn_s_barrier();
    asm volatile("" ::: "memory");
}

// issue one hidden layer's A-frag loads (consumed one phase later)
static __device__ __forceinline__ void prefA(const ushort* __restrict__ Wm,
        int wvm, int l, short8 (&__restrict__ wf)[8])
{
    const short8* fb = (const short8*)(Wm + (wvm << 12));   // rb = wvm
#pragma unroll
    for (int kc = 0; kc < 8; ++kc) wf[kc] = fb[kc * 64 + l];
}

// layer 1: [t,S] -> 128 rows; wave wvm owns rows 32*wvm..+32 (one short8 per cc)
__device__ __forceinline__ void layer1(const float* __restrict__ Win, const float* __restrict__ bin_,
        float t, const float* __restrict__ sScur, char* __restrict__ lds, int wl1, int wvm, int l)
{
    const int g = l >> 4, c15 = l & 15;
    const int r0 = (wvm << 5) + (g << 3);
    float a8[8], w1[8];
#pragma unroll
    for (int jj = 0; jj < 8; ++jj) {
        const int r = r0 + jj;
        a8[jj] = fmaf(Win[2*r], t, bin_[r]);
        w1[jj] = Win[2*r + 1];
    }
#pragma unroll
    for (int cc = 0; cc < 4; ++cc) {
        const float S = sScur[c15 + (cc << 4)];
        short8 v;
#pragma unroll
        for (int jj = 0; jj < 8; ++jj) {
            float h = fmaf(w1[jj], S, a8[jj]);
            h = fmaxf(h, 0.01f * h);            // leaky relu
            v[jj] = f2bf(h);
        }
        *(short8*)__builtin_assume_aligned(lds + wl1 + (cc << 12), 16) = v;
    }
}

// hidden 128x128 layer: prefetched A-frags, precomputed LDS addrs, bias as C-init, 4 acc chains
__device__ __forceinline__ void hidden32(char* __restrict__ lds,
        const int (&__restrict__ rdk)[8], const int (&__restrict__ wrq)[4],
        int rdImm, int wrImm,
        const short8 (&__restrict__ wf)[8], const float* __restrict__ bias,
        int wvm, int l, int l5)
{
    f32x16 a0e, a1e;
    f32x16 a0o = {0,0,0,0,0,0,0,0,0,0,0,0,0,0,0,0};
    f32x16 a1o = a0o;
#pragma unroll
    for (int q = 0; q < 4; ++q) {
        const f32x4v bq = *(const f32x4v*)&bias[(wvm << 5) + (q << 3) + (l5 << 2)];
#pragma unroll
        for (int ii = 0; ii < 4; ++ii) {
            a0e[(q << 2) + ii] = bq[ii];
            a1e[(q << 2) + ii] = bq[ii];
        }
    }
#pragma unroll
    for (int kc = 0; kc < 8; kc += 2) {
        short8 b0e = ldsr16(lds + rdk[kc]     + rdImm);
        short8 b1e = ldsr16(lds + rdk[kc]     + rdImm + 8192);
        short8 b0o = ldsr16(lds + rdk[kc + 1] + rdImm);
        short8 b1o = ldsr16(lds + rdk[kc + 1] + rdImm + 8192);
        a0e = __builtin_amdgcn_mfma_f32_32x32x16_bf16(wf[kc],     b0e, a0e, 0, 0, 0);
        a1e = __builtin_amdgcn_mfma_f32_32x32x16_bf16(wf[kc],     b1e, a1e, 0, 0, 0);
        a0o = __builtin_amdgcn_mfma_f32_32x32x16_bf16(wf[kc + 1], b0o, a0o, 0, 0, 0);
        a1o = __builtin_amdgcn_mfma_f32_32x32x16_bf16(wf[kc + 1], b1o, a1o, 0, 0, 0);
    }
    const f32x16 acc0 = a0e + a0o;
    const f32x16 acc1 = a1e + a1o;
#pragma unroll
    for (int q = 0; q < 4; ++q) {
        short4v o0, o1;
#pragma unroll
        for (int ii = 0; ii < 4; ++ii) {
            float x0 = acc0[(q << 2) + ii]; o0[ii] = f2bf(fmaxf(x0, 0.01f * x0));
            float x1 = acc1[(q << 2) + ii]; o1[ii] = f2bf(fmaxf(x1, 0.01f * x1));
        }
        ldsw8(lds + wrq[q] + wrImm,        o0);
        ldsw8(lds + wrq[q] + wrImm + 8192, o1);
    }
}

__global__ __launch_bounds__(512, 2)
void sim_kernel(const float* __restrict__ normals, const float* __restrict__ strikes,
                const float* __restrict__ levWin, const float* __restrict__ levbin,
                const float* __restrict__ levbh,  const float* __restrict__ levWout,
                const float* __restrict__ levbout,
                const float* __restrict__ hedWin, const float* __restrict__ hedbin,
                const float* __restrict__ hedbh,  const float* __restrict__ hedbout,
                const ushort* __restrict__ WF, double* __restrict__ accD)
{
    __shared__ char lds[66560];
    float* sSb = (float*)(lds + LDS_SS);   // [2][64]
    float* sHc = (float*)(lds + LDS_HC);   // [64]

    const int tid  = threadIdx.x;
    const int wv   = tid >> 6;
    const int half = wv >> 2;      // 0 = lev chain, 1 = hed chain
    const int wvm  = wv & 3;
    const int l    = tid & 63;
    const int g    = l >> 4;
    const int c15  = l & 15;
    const int c0   = l & 31;
    const int l5   = l >> 5;
    const int bp0  = blockIdx.x * 64;

    // ---- loop-invariant swizzled LDS addresses (bytes) ----
    const int chainoff = half << 14;
    const int rbase = chainoff + (c0 << 8) + ((l5 ^ (c0 & 1)) << 4);
    const int pxor  = ((c0 >> 1) & 7) << 5;
    int rdk[8];
#pragma unroll
    for (int kc = 0; kc < 8; ++kc) rdk[kc] = rbase + ((kc << 5) ^ pxor);
    int wrq[4];
#pragma unroll
    for (int q = 0; q < 4; ++q)
        wrq[q] = chainoff + (c0 << 8) + (l5 << 3)
               + ((q ^ (c0 & 3)) << 4) + ((wvm ^ ((c0 >> 2) & 3)) << 6);
    const int wl1 = chainoff + (c15 << 8) + ((g ^ (c15 & 3)) << 4)
                  + ((wvm ^ ((c15 >> 2) & 3)) << 6);
    int rout[4];
    if (half == 0) {
        const int cl = c15 + (wvm << 4);
        const int ob = LDS_L1 + (cl << 8) + ((g ^ ((cl >> 2) & 3)) << 6);
#pragma unroll
        for (int kb = 0; kb < 4; ++kb) rout[kb] = ob + ((kb ^ (cl & 3)) << 4);
    } else {
        const int ob = LDS_H1 + (c15 << 8) + (((l >> 4) ^ (c15 & 3)) << 4);
        const int px2 = ((c15 >> 2) & 3) << 6;
#pragma unroll
        for (int kcq = 0; kcq < 4; ++kcq) rout[kcq] = ob + ((kcq << 6) ^ px2);
    }

    if (tid < 64) sSb[tid] = 1.0f;   // sS[0]
    float hedg[4][4];
#pragma unroll
    for (int a = 0; a < 4; ++a)
#pragma unroll
        for (int b = 0; b < 4; ++b) hedg[a][b] = 0.f;
    float dfim1 = 1.0f;

    short8 wfA[8], wfB[8];   // phase-ahead A-frag pipeline (16+16 VGPR)
    __syncthreads();

    for (int i = 1; i <= 96; ++i) {
        const int idx = (i - 1) / 12;
        const float t = (float)(i - 1) * DT_F;
        const float* sScur = sSb + (((i - 1) & 1) << 6);
        float* sSnxt = sSb + ((i & 1) << 6);
        const ushort* WFi = WF + (size_t)idx * 106496;

        const float* Win  = (half ? hedWin : levWin) + idx * 256;
        const float* binp = (half ? hedbin : levbin) + (idx << 7);
        const float* bh   = (half ? hedbh  : levbh)  + idx * 384;
        const ushort* Wm  = WFi + ((half * 3) << 14);

        // W1: issue h1 frag loads; layer1 VALU hides them; normals prefetch (lev)
        prefA(Wm, wvm, l, wfA);
        layer1(Win, binp, t, sScur, lds, wl1, wvm, l);
        float nrm = 0.f;
        if (half == 0) nrm = normals[(size_t)(i - 1) * 16384 + bp0 + c15 + (wvm << 4)];
        soft_barrier();                                     // b1

        // W2: issue h2 loads; compute h1
        prefA(Wm + 16384, wvm, l, wfB);
        hidden32(lds, rdk, wrq, 0,     32768, wfA, bh,       wvm, l, l5);
        soft_barrier();                                     // b2

        // W3: issue h3 loads; compute h2
        prefA(Wm + 32768, wvm, l, wfA);
        hidden32(lds, rdk, wrq, 32768, 0,     wfB, bh + 128, wvm, l, l5);
        soft_barrier();                                     // b3

        // W4: issue hed-out operand loads; compute h3
        short8 wOut[4];
        f32x4v bo4;
        if (half == 1) {
            const short8* fo = (const short8*)(WFi + 98304 + (wvm << 11));
#pragma unroll
            for (int kcq = 0; kcq < 4; ++kcq) wOut[kcq] = fo[kcq * 64 + l];
            bo4 = *(const f32x4v*)&hedbout[(idx << 6) + (wvm << 4) + (g << 2)];
        }
        hidden32(lds, rdk, wrq, 0,     32768, wfA, bh + 256, wvm, l, l5);
        soft_barrier();                                     // b4

        const float dfi = dfim1 * DF_F;
        f32x4v acc0, acc1, acc2, acc3;
        if (half == 0) {
            // lev-out (1x128 dot) + SDE; wave wvm owns cols 16*wvm..+16
            const float* Wo = levWout + (idx << 7);
            float wk[32];
#pragma unroll
            for (int kb = 0; kb < 8; ++kb)
                *(f32x4v*)&wk[4 * kb] = *(const f32x4v*)&Wo[(g << 5) + (kb << 2)];
            const int c = c15 + (wvm << 4);
            float p = 0.f;
#pragma unroll
            for (int kb = 0; kb < 4; ++kb) {
                short8 hv = ldsr16(lds + rout[kb]);   // logical kb (addr pre-XORed)
#pragma unroll
                for (int j = 0; j < 8; ++j) p = fmaf(bf2f(hv[j]), wk[(kb << 3) + j], p);
            }
            p += __shfl_xor(p, 16);
            p += __shfl_xor(p, 32);
            p += levbout[idx];
            const float lv = (p > 20.f) ? p : __logf(1.f + __expf(p));   // softplus
            const float S = sScur[c];
            const float drift = S * RFR_F / (1.f + fabsf(S * RFR_F) * SQDT_F);
            const float dif   = S * lv    / (1.f + fabsf(S * lv)   * SQDT_F);
            const float dW = SQDT_F * nrm;
            const float Sn = S + drift * DT_F + dif * dW;
            if (g == 0) { sSnxt[c] = Sn; sHc[c] = dfim1 * (S * dif) * dW; }
        } else {
            // hed-out 64x128 via 16x16x32 MFMA; prefetched wOut, bias as C-init
            acc0 = bo4; acc1 = bo4; acc2 = bo4; acc3 = bo4;
            __builtin_amdgcn_s_setprio(1);
#pragma unroll
            for (int kcq = 0; kcq < 4; ++kcq) {
                short8 b0 = ldsr16(lds + rout[kcq]);
                short8 b1 = ldsr16(lds + rout[kcq] + 4096);
                short8 b2 = ldsr16(lds + rout[kcq] + 8192);
                short8 b3 = ldsr16(lds + rout[kcq] + 12288);
                acc0 = __builtin_amdgcn_mfma_f32_16x16x32_bf16(wOut[kcq], b0, acc0, 0, 0, 0);
                acc1 = __builtin_amdgcn_mfma_f32_16x16x32_bf16(wOut[kcq], b1, acc1, 0, 0, 0);
                acc2 = __builtin_amdgcn_mfma_f32_16x16x32_bf16(wOut[kcq], b2, acc2, 0, 0, 0);
                acc3 = __builtin_amdgcn_mfma_f32_16x16x32_bf16(wOut[kcq], b3, acc3, 0, 0, 0);
            }
            __builtin_amdgcn_s_setprio(0);
        }
        soft_barrier();                                     // b5

        if (half == 1) {
            const float hc0 = sHc[c15], hc1 = sHc[16 + c15], hc2 = sHc[32 + c15], hc3 = sHc[48 + c15];
#pragma unroll
            for (int ii = 0; ii < 4; ++ii) {
                hedg[0][ii] = fmaf(hc0, acc0[ii], hedg[0][ii]);
                hedg[1][ii] = fmaf(hc1, acc1[ii], hedg[1][ii]);
                hedg[2][ii] = fmaf(hc2, acc2[ii], hedg[2][ii]);
                hedg[3][ii] = fmaf(hc3, acc3[ii], hedg[3][ii]);
            }
            if ((i % 12) == 0) {
                const int m = i / 12 - 1;
                const int isel = m & 3;
                const bool active = ((m >> 2) == (g & 1));
                const int ks = (wvm << 1) + (g >> 1);
                float s_ = 0.f, q_ = 0.f;
                if (active) {
                    const float K = strikes[ks];
#pragma unroll
                    for (int ct = 0; ct < 4; ++ct) {
                        const float* hrow = hedg[ct];
                        const float hv = (isel == 0) ? hrow[0] : (isel == 1) ? hrow[1]
                                        : (isel == 2) ? hrow[2] : hrow[3];
                        const float Sn = sSnxt[(ct << 4) + c15];
                        const float sim = dfi * fmaxf(Sn - K, 0.f) - hv;
                        s_ += sim; q_ += sim * sim;
                    }
                }
#pragma unroll
                for (int off = 1; off < 16; off <<= 1) {
                    s_ += __shfl_xor(s_, off);
                    q_ += __shfl_xor(q_, off);
                }
                if (active && c15 == 0) {
                    const int rep = blockIdx.x & 31;
                    atomicAdd(&accD[rep * 128 + ks * 8 + m], (double)s_);
                    atomicAdd(&accD[rep * 128 + 64 + ks * 8 + m], (double)q_);
                }
            }
        }
        dfim1 = dfi;
    }
}

// prep: pack bf16 weights into MFMA fragment order + zero accumulators (unchanged layout)
__global__ void prep_kernel(const float* __restrict__ levWh, const float* __restrict__ hedWh,
                            const float* __restrict__ hedWout,
                            ushort* __restrict__ WF, double* __restrict__ accD)
{
    const long long stride = (long long)gridDim.x * blockDim.x;
    const long long t0 = (long long)blockIdx.x * blockDim.x + threadIdx.x;
    for (long long e = t0; e < 851968LL; e += stride) {
        const int idx = (int)(e / 106496);
        const int rem = (int)(e % 106496);
        float val;
        if (rem < 98304) {                        // 6 hidden matrices
            const int m    = rem >> 14;
            const int r2   = rem & 16383;
            const int slot = r2 >> 9;             // rb*8 + kc
            const int rb   = slot >> 3;
            const int kc   = slot & 7;
            const int lane = (r2 >> 3) & 63;
            const int j    = r2 & 7;
            const int r = (rb << 5) + (lane & 31);
            const int k = (kc << 4) + ((lane >> 5) << 3) + j;
            const float* src = (m < 3) ? levWh : hedWh;
            const int mm = (m < 3) ? m : m - 3;
            val = src[(((idx * 3 + mm) << 7) + r) * 128 + k];
        } else {                                  // hed-out 64x128
            const int r3   = rem - 98304;
            const int slot = r3 >> 9;             // rb*4 + kcq
            const int rb   = slot >> 2;
            const int kcq  = slot & 3;
            const int lane = (r3 >> 3) & 63;
            const int j    = r3 & 7;
            const int r = (rb << 4) + (lane & 15);
            const int k = (kcq << 5) + ((lane >> 4) << 3) + j;
            val = hedWout[(idx << 13) + (r << 7) + k];
        }
        WF[e] = (ushort)f2bf(val);
    }
    for (long long e = t0; e < 4096; e += stride) accD[e] = 0.0;
}

__global__ void finalize_kernel(const double* __restrict__ accD, float* __restrict__ out)
{
    const int t = threadIdx.x;
    if (t < 64) {
        double s = 0.0, q = 0.0;
        for (int rep = 0; rep < 32; ++rep) {
            s += accD[rep * 128 + t];
            q += accD[rep * 128 + 64 + t];
        }
        out[t]      = (float)(s / 16384.0);
        out[64 + t] = (float)((q - s * s / 16384.0) / 16383.0);
    }
}

extern "C" void kernel_launch(void* const* d_in, const int* in_sizes, int n_in,
                              void* d_out, int out_size, void* d_ws, size_t ws_size,
                              hipStream_t stream)
{
    const float* normals = (const float*)d_in[0];
    const float* strikes = (const float*)d_in[1];
    const float* levWin  = (const float*)d_in[2];
    const float* levbin  = (const float*)d_in[3];
    const float* levWh   = (const float*)d_in[4];
    const float* levbh   = (const float*)d_in[5];
    const float* levWout = (const float*)d_in[6];
    const float* levbout = (const float*)d_in[7];
    const float* hedWin  = (const float*)d_in[8];
    const float* hedbin  = (const float*)d_in[9];
    const float* hedWh   = (const float*)d_in[10];
    const float* hedbh   = (const float*)d_in[11];
    const float* hedWout = (const float*)d_in[12];
    const float* hedbout = (const float*)d_in[13];

    ushort* WF   = (ushort*)d_ws;                      // 851,968 ushorts = 1,703,936 B
    double* accD = (double*)((char*)d_ws + 1703936);   // 4096 doubles

    prep_kernel<<<1024, 256, 0, stream>>>(levWh, hedWh, hedWout, WF, accD);
    sim_kernel<<<256, 512, 0, stream>>>(normals, strikes,
                                        levWin, levbin, levbh, levWout, levbout,
                                        hedWin, hedbin, hedbh, hedbout,
                                        WF, accD);
    finalize_kernel<<<1, 64, 0, stream>>>(accD, (float*)d_out);
}